// Round 5
// baseline (122.202 us; speedup 1.0000x reference)
//
#include <hip/hip_runtime.h>

typedef unsigned short u16;
typedef __attribute__((ext_vector_type(8))) short short8;
typedef __attribute__((ext_vector_type(4))) float f32x4;
typedef __attribute__((ext_vector_type(4))) u16 u16x4;

#define BB 4
#define LL 16
#define DD 512
#define NH 8
#define HDIM 64
#define NSEQ 1024
#define E3 1536
#define INV_SCALE 0.04419417382415922f

__device__ __forceinline__ u16 f2bf(float f) {
  union { float f; unsigned u; } v; v.f = f;
  unsigned u = v.u;
  unsigned r = u + 0x7fffu + ((u >> 16) & 1u);
  return (u16)(r >> 16);
}

__device__ __forceinline__ unsigned cvtpk(float lo, float hi) {
  unsigned r;
  asm("v_cvt_pk_bf16_f32 %0, %1, %2" : "=v"(r) : "v"(lo), "v"(hi));
  return r;
}

__device__ __forceinline__ uint4 pack8(float4 a, float4 b) {
  uint4 r;
  r.x = (unsigned)f2bf(a.x) | ((unsigned)f2bf(a.y) << 16);
  r.y = (unsigned)f2bf(a.z) | ((unsigned)f2bf(a.w) << 16);
  r.z = (unsigned)f2bf(b.x) | ((unsigned)f2bf(b.y) << 16);
  r.w = (unsigned)f2bf(b.z) | ((unsigned)f2bf(b.w) << 16);
  return r;
}

__device__ __forceinline__ void stage16(const u16* g, u16* l) {
  __builtin_amdgcn_global_load_lds((const __attribute__((address_space(1))) unsigned int*)g,
                                   (__attribute__((address_space(3))) unsigned int*)l,
                                   16, 0, 0);
}

// ---------------- kernel 1: fp32 -> bf16 of x, W_qkv ----------------
__global__ __launch_bounds__(256) void prep_convert(const float* __restrict__ x,
                                                    const float* __restrict__ w,
                                                    u16* __restrict__ xbf,
                                                    u16* __restrict__ wbf) {
  const int nx = (4096 * DD) / 4;   // 524288
  const int nw = (E3 * DD) / 4;     // 196608
  int i = blockIdx.x * 256 + threadIdx.x;
  const float4* src;
  uint2* dst;
  int j;
  if (i < nx) { src = (const float4*)x; dst = (uint2*)xbf; j = i; }
  else if (i < nx + nw) { src = (const float4*)w; dst = (uint2*)wbf; j = i - nx; }
  else return;
  float4 v = src[j];
  unsigned lo = (unsigned)f2bf(v.x) | ((unsigned)f2bf(v.y) << 16);
  unsigned hi = (unsigned)f2bf(v.z) | ((unsigned)f2bf(v.w) << 16);
  dst[j] = make_uint2(lo, hi);
}

// ---------------- kernel 2: tqkv via MFMA, fp32 inputs converted in-register ----------------
__global__ __launch_bounds__(256) void tproj_mfma(const float* __restrict__ te,
                                                  const float* __restrict__ wt,
                                                  float* __restrict__ tq) {
  __shared__ u16 At[64][72];
  __shared__ u16 Bt[64][72];
  int bn = blockIdx.x;            // 0..2
  int tid = threadIdx.x;
  int w = tid >> 6, l = tid & 63;
  int l15 = l & 15, l16 = l >> 4;
  int r0 = tid >> 3, c0 = (tid & 7) * 8;
  f32x4 acc[4] = {};
  for (int kt = 0; kt < DD; kt += 64) {
    {
      const float* ta = &te[(size_t)r0 * DD + kt + c0];
      const float* tb = &te[(size_t)(r0 + 32) * DD + kt + c0];
      *(uint4*)&At[r0][c0]      = pack8(*(const float4*)ta, *(const float4*)(ta + 4));
      *(uint4*)&At[r0 + 32][c0] = pack8(*(const float4*)tb, *(const float4*)(tb + 4));
      const float* wa = &wt[(size_t)(bn * 64 + r0) * DD + kt + c0];
      const float* wb_ = &wt[(size_t)(bn * 64 + r0 + 32) * DD + kt + c0];
      *(uint4*)&Bt[r0][c0]      = pack8(*(const float4*)wa, *(const float4*)(wa + 4));
      *(uint4*)&Bt[r0 + 32][c0] = pack8(*(const float4*)wb_, *(const float4*)(wb_ + 4));
    }
    __syncthreads();
#pragma unroll
    for (int ks = 0; ks < 2; ++ks) {
      short8 bfr = *(const short8*)&Bt[w * 16 + l15][ks * 32 + l16 * 8];
#pragma unroll
      for (int mt = 0; mt < 4; ++mt) {
        short8 afr = *(const short8*)&At[mt * 16 + l15][ks * 32 + l16 * 8];
        acc[mt] = __builtin_amdgcn_mfma_f32_16x16x32_bf16(afr, bfr, acc[mt], 0, 0, 0);
      }
    }
    __syncthreads();
  }
  int e = bn * 64 + w * 16 + l15;
#pragma unroll
  for (int mt = 0; mt < 4; ++mt)
#pragma unroll
    for (int r = 0; r < 4; ++r)
      tq[(mt * 16 + l16 * 4 + r) * 192 + e] = acc[mt][r];
}

// ---------------- kernel 3: qkv GEMM (2-phase pipelined) + time add + scatter ----------------
__global__ __launch_bounds__(256) void gemm_qkv(const u16* __restrict__ xb,
                                                const u16* __restrict__ wb,
                                                const float* __restrict__ tq,
                                                u16* __restrict__ qp,
                                                u16* __restrict__ kp,
                                                u16* __restrict__ vt) {
  __shared__ u16 As[2][128][72];
  __shared__ u16 Bs[2][128][72];
  int bn = blockIdx.x;
  int bm = blockIdx.y;
  int tid = threadIdx.x;
  int w = tid >> 6, l = tid & 63;
  int wr = w >> 1, wc = w & 1;
  int l15 = l & 15, l16 = l >> 4;
  int r0 = tid >> 3, c0 = (tid & 7) * 8;

  f32x4 acc[4][4] = {};
  uint4 ra[4], rb[4];

#define LOADT(kt)                                                                    \
  {                                                                                  \
    _Pragma("unroll") for (int c = 0; c < 4; ++c) {                                  \
      ra[c] = *(const uint4*)&xb[(size_t)(bm * 128 + c * 32 + r0) * DD + (kt) + c0]; \
      rb[c] = *(const uint4*)&wb[(size_t)(bn * 128 + c * 32 + r0) * DD + (kt) + c0]; \
    }                                                                                \
  }
#define STORET(buf)                                                                  \
  {                                                                                  \
    _Pragma("unroll") for (int c = 0; c < 4; ++c) {                                  \
      *(uint4*)&As[buf][c * 32 + r0][c0] = ra[c];                                    \
      *(uint4*)&Bs[buf][c * 32 + r0][c0] = rb[c];                                    \
    }                                                                                \
  }

  LOADT(0);
  STORET(0);
  __syncthreads();
  int cur = 0;
#pragma unroll
  for (int i = 0; i < 8; ++i) {
    if (i < 7) LOADT((i + 1) * 64);
#pragma unroll
    for (int ks = 0; ks < 2; ++ks) {
      short8 af[4], bf[4];
#pragma unroll
      for (int mt = 0; mt < 4; ++mt)
        af[mt] = *(const short8*)&As[cur][wr * 64 + mt * 16 + l15][ks * 32 + l16 * 8];
#pragma unroll
      for (int nt = 0; nt < 4; ++nt)
        bf[nt] = *(const short8*)&Bs[cur][wc * 64 + nt * 16 + l15][ks * 32 + l16 * 8];
#pragma unroll
      for (int mt = 0; mt < 4; ++mt)
#pragma unroll
        for (int nt = 0; nt < 4; ++nt)
          acc[mt][nt] = __builtin_amdgcn_mfma_f32_16x16x32_bf16(af[mt], bf[nt], acc[mt][nt], 0, 0, 0);
    }
    if (i < 7) STORET(cur ^ 1);
    __syncthreads();
    cur ^= 1;
  }
#undef LOADT
#undef STORET

  int part = bn >> 2;
#pragma unroll
  for (int mt = 0; mt < 4; ++mt) {
    int m0 = bm * 128 + wr * 64 + mt * 16 + l16 * 4;
    int b = m0 >> 10;
    int li = (m0 >> 6) & 15;
    int nn0 = m0 & 1023;
    const float* tqrow = &tq[(b * LL + li) * 192 + part * 64];
#pragma unroll
    for (int nt = 0; nt < 4; ++nt) {
      int din = (bn & 3) * 128 + wc * 64 + nt * 16 + l15;
      int hh = din >> 6, hd = din & 63;
      float t = tqrow[hd];
      size_t bh = (size_t)(b * NH + hh);
      if (part == 2) {
        u16x4 pk;
#pragma unroll
        for (int r = 0; r < 4; ++r) pk[r] = f2bf(acc[mt][nt][r] + t);
        *(u16x4*)&vt[(bh * HDIM + hd) * NSEQ + nn0] = pk;
      } else {
        u16* dst = (part == 0) ? qp : kp;
#pragma unroll
        for (int r = 0; r < 4; ++r)
          dst[(bh * NSEQ + nn0 + r) * HDIM + hd] = f2bf(acc[mt][nt][r] + t);
      }
    }
  }
}

// ---------------- kernel 4: flash attention, S^T form + counted-vmcnt pipeline ----------------
// S^T = mfma(K,Q): lane owns P[q=l15][16 keys] -> softmax is per-lane, P->PV needs
// no cross-lane movement (cvt_pk + permuted V fragment reads). Depth-2 stage pipeline
// with vmcnt(4) (never 0) in the loop.
__global__ __launch_bounds__(256, 2) void attn_kernel(const u16* __restrict__ qp,
                                                      const u16* __restrict__ kp,
                                                      const u16* __restrict__ vt,
                                                      const int* __restrict__ pos,
                                                      const float* __restrict__ emb,
                                                      float* __restrict__ out) {
  __shared__ __align__(16) u16 Kt[2][64][64];
  __shared__ __align__(16) u16 Vt[2][64][64];
  __shared__ __align__(16) float Ot[4][16][68];

  int blk = blockIdx.x;
  int bhid = blk & 31;
  int qf = 15 - (blk >> 5);
  int b = bhid >> 3, h = bhid & 7;
  int tid = threadIdx.x;
  int rg = tid >> 6;
  int l = tid & 63;
  int l15 = l & 15, l16 = l >> 4;
  int srow = l >> 3, c8 = l & 7;
  int schunk = c8 ^ srow;
  int swzA = (l15 & 7) << 4;

  size_t bh = (size_t)(b * NH + h);
  const u16* Kb = kp + bh * NSEQ * HDIM;
  const u16* Vb = vt + bh * HDIM * NSEQ;
  int rowl0 = rg * 16 + srow;
  int rowl1 = rowl0 + 8;

#define STAGE(kf_, buf_)                                                   \
  {                                                                        \
    stage16(Kb + ((kf_) * 64 + rowl0) * HDIM + schunk * 8,                 \
            &Kt[buf_][rg * 16 + 0][0] + l * 8);                            \
    stage16(Kb + ((kf_) * 64 + rowl1) * HDIM + schunk * 8,                 \
            &Kt[buf_][rg * 16 + 8][0] + l * 8);                            \
    stage16(Vb + (size_t)rowl0 * NSEQ + (kf_) * 64 + schunk * 8,           \
            &Vt[buf_][rg * 16 + 0][0] + l * 8);                            \
    stage16(Vb + (size_t)rowl1 * NSEQ + (kf_) * 64 + schunk * 8,           \
            &Vt[buf_][rg * 16 + 8][0] + l * 8);                            \
  }

  // Q B-fragments (q = l15), registers for the whole kernel
  const u16* Qg = qp + (bh * NSEQ + qf * 64 + rg * 16) * HDIM;
  short8 aq[2];
  aq[0] = *(const short8*)&Qg[l15 * HDIM + l16 * 8];
  aq[1] = *(const short8*)&Qg[l15 * HDIM + 32 + l16 * 8];

  // depth-2 prologue
  STAGE(0, 0);
  if (qf > 0) STAGE(1, 1);

  // bias^T: bfragT[r] = bias[q=l15][kf=l16*4+r] via mfma(emb-rows, Q)
  int pp = pos[(b * LL + qf) * LL + l15];
  pp = (pp < -8 ? -8 : (pp > 8 ? 8 : pp)) + 8;
  const float* ev = emb + pp * HDIM;
  f32x4 bfragT = {};
#pragma unroll
  for (int ks = 0; ks < 2; ++ks) {
    float4 e0 = *(const float4*)&ev[ks * 32 + l16 * 8];
    float4 e1 = *(const float4*)&ev[ks * 32 + l16 * 8 + 4];
    short8 ef;
    ef[0] = (short)f2bf(e0.x); ef[1] = (short)f2bf(e0.y);
    ef[2] = (short)f2bf(e0.z); ef[3] = (short)f2bf(e0.w);
    ef[4] = (short)f2bf(e1.x); ef[5] = (short)f2bf(e1.y);
    ef[6] = (short)f2bf(e1.z); ef[7] = (short)f2bf(e1.w);
    bfragT = __builtin_amdgcn_mfma_f32_16x16x32_bf16(ef, aq[ks], bfragT, 0, 0, 0);
  }

  f32x4 o[4] = {};
  float lsum = 0.f;

  if (qf > 0) { asm volatile("s_waitcnt vmcnt(4)" ::: "memory"); }
  else        { asm volatile("s_waitcnt vmcnt(0)" ::: "memory"); }
  __syncthreads();

  for (int kf = 0; kf <= qf; ++kf) {
    int cur = kf & 1;
    const char* ktb = (const char*)&Kt[cur][0][0];
    const char* vtb = (const char*)&Vt[cur][0][0];

    // S^T = mfma(K-rows, Q): s[nt][r] = S[q=l15][key = nt*16 + l16*4 + r]
    f32x4 s[4] = {};
    __builtin_amdgcn_s_setprio(1);
#pragma unroll
    for (int ks = 0; ks < 2; ++ks)
#pragma unroll
      for (int nt = 0; nt < 4; ++nt) {
        short8 kfrag = *(const short8*)(ktb + (nt * 16 + l15) * 128 + ((ks * 64 + l16 * 16) ^ swzA));
        s[nt] = __builtin_amdgcn_mfma_f32_16x16x32_bf16(kfrag, aq[ks], s[nt], 0, 0, 0);
      }
    __builtin_amdgcn_s_setprio(0);

    // one bpermute for the frame bias (per-lane q)
    float bb = __shfl(bfragT[kf & 3], ((kf >> 2) << 4) | l15) * INV_SCALE;

    float pv[4][4];
#pragma unroll
    for (int nt = 0; nt < 4; ++nt)
#pragma unroll
      for (int r = 0; r < 4; ++r) {
        float p = __expf(fmaf(s[nt][r], INV_SCALE, bb));
        pv[nt][r] = p;
        lsum += p;
      }

    // PV: pack own P values (no cross-lane), permuted V fragment reads
#pragma unroll
    for (int w32 = 0; w32 < 2; ++w32) {
      union { unsigned u[4]; short8 s8; } pf;
      pf.u[0] = cvtpk(pv[w32 * 2][0], pv[w32 * 2][1]);
      pf.u[1] = cvtpk(pv[w32 * 2][2], pv[w32 * 2][3]);
      pf.u[2] = cvtpk(pv[w32 * 2 + 1][0], pv[w32 * 2 + 1][1]);
      pf.u[3] = cvtpk(pv[w32 * 2 + 1][2], pv[w32 * 2 + 1][3]);
      int off0 = w32 * 64 + l16 * 8;
      int cp = off0 & ~15, sub = off0 & 15;
      __builtin_amdgcn_s_setprio(1);
#pragma unroll
      for (int dt = 0; dt < 4; ++dt) {
        int d = dt * 16 + l15;
        int sx = (d & 7) << 4;
        union { uint2 h2[2]; short8 s8; } vf;
        vf.h2[0] = *(const uint2*)(vtb + d * 128 + (cp ^ sx) + sub);
        vf.h2[1] = *(const uint2*)(vtb + d * 128 + ((cp + 32) ^ sx) + sub);
        o[dt] = __builtin_amdgcn_mfma_f32_16x16x32_bf16(vf.s8, pf.s8, o[dt], 0, 0, 0);
      }
      __builtin_amdgcn_s_setprio(0);
    }

    if (kf < qf) {
      __syncthreads();                       // all waves done reading buf cur
      if (kf + 2 <= qf) {
        STAGE(kf + 2, cur);                  // reuse cur for frame kf+2
        asm volatile("s_waitcnt vmcnt(4)" ::: "memory");   // STAGE(kf+1) landed
      } else {
        asm volatile("s_waitcnt vmcnt(0)" ::: "memory");
      }
      __syncthreads();
    }
  }
#undef STAGE

  // finish softmax denominator: q=l15 partials live in the 4 lanes l15+16*{0..3}
  lsum += __shfl_xor(lsum, 16);
  lsum += __shfl_xor(lsum, 32);
  float inv = 1.0f / lsum;

  // O^T -> O via per-wave LDS transpose (wave-private, no barrier)
#pragma unroll
  for (int dt = 0; dt < 4; ++dt)
#pragma unroll
    for (int r = 0; r < 4; ++r)
      Ot[rg][l15][dt * 16 + l16 * 4 + r] = o[dt][r] * inv;

  float* outp = out + ((size_t)(b * LL + qf) * 64 + rg * 16) * DD + h * 64;
#pragma unroll
  for (int rr = 0; rr < 4; ++rr) {
    int q = rr * 4 + l16;
    float4 v = *(const float4*)&Ot[rg][q][l15 * 4];
    *(float4*)&outp[(size_t)q * DD + l15 * 4] = v;
  }
}

// ---------------- launcher ----------------
extern "C" void kernel_launch(void* const* d_in, const int* in_sizes, int n_in,
                              void* d_out, int out_size, void* d_ws, size_t ws_size,
                              hipStream_t stream) {
  const float* x    = (const float*)d_in[0];
  const float* te   = (const float*)d_in[1];
  const int*   pos  = (const int*)d_in[2];
  // d_in[3] = mask: structurally frame-causal (tril)
  const float* wqkv = (const float*)d_in[4];
  const float* wt   = (const float*)d_in[5];
  const float* emb  = (const float*)d_in[6];
  float* out = (float*)d_out;
  char* ws = (char*)d_ws;

  const size_t OFF_XBF = 0;
  const size_t OFF_WBF  = OFF_XBF + (size_t)4096 * DD * 2;
  const size_t OFF_TQ   = OFF_WBF + (size_t)E3 * DD * 2;
  const size_t OFF_QKV  = OFF_TQ + (size_t)64 * 192 * 4;
  const size_t PLANE = (size_t)BB * NH * NSEQ * HDIM;

  u16*   xbf  = (u16*)(ws + OFF_XBF);
  u16*   wbf  = (u16*)(ws + OFF_WBF);
  float* tq   = (float*)(ws + OFF_TQ);
  u16*   qpl  = (u16*)(ws + OFF_QKV);
  u16*   kpl  = qpl + PLANE;
  u16*   vtl  = qpl + 2 * PLANE;

  prep_convert<<<2816, 256, 0, stream>>>(x, wqkv, xbf, wbf);
  tproj_mfma<<<3, 256, 0, stream>>>(te, wt, tq);
  gemm_qkv<<<dim3(12, 32), 256, 0, stream>>>(xbf, wbf, tq, qpl, kpl, vtl);
  attn_kernel<<<512, 256, 0, stream>>>(qpl, kpl, vtl, pos, emb, out);
}

// Round 6
// 120.430 us; speedup vs baseline: 1.0147x; 1.0147x over previous
//
#include <hip/hip_runtime.h>

typedef unsigned short u16;
typedef __attribute__((ext_vector_type(8))) short short8;
typedef __attribute__((ext_vector_type(4))) float f32x4;
typedef __attribute__((ext_vector_type(4))) u16 u16x4;

#define BB 4
#define LL 16
#define DD 512
#define NH 8
#define HDIM 64
#define NSEQ 1024
#define E3 1536
#define INV_SCALE 0.04419417382415922f

__device__ __forceinline__ u16 f2bf(float f) {
  union { float f; unsigned u; } v; v.f = f;
  unsigned u = v.u;
  unsigned r = u + 0x7fffu + ((u >> 16) & 1u);
  return (u16)(r >> 16);
}

__device__ __forceinline__ unsigned cvtpk(float lo, float hi) {
  unsigned r;
  asm("v_cvt_pk_bf16_f32 %0, %1, %2" : "=v"(r) : "v"(lo), "v"(hi));
  return r;
}

__device__ __forceinline__ uint4 pack8(float4 a, float4 b) {
  uint4 r;
  r.x = (unsigned)f2bf(a.x) | ((unsigned)f2bf(a.y) << 16);
  r.y = (unsigned)f2bf(a.z) | ((unsigned)f2bf(a.w) << 16);
  r.z = (unsigned)f2bf(b.x) | ((unsigned)f2bf(b.y) << 16);
  r.w = (unsigned)f2bf(b.z) | ((unsigned)f2bf(b.w) << 16);
  return r;
}

__device__ __forceinline__ void stage16(const u16* g, u16* l) {
  __builtin_amdgcn_global_load_lds((const __attribute__((address_space(1))) unsigned int*)g,
                                   (__attribute__((address_space(3))) unsigned int*)l,
                                   16, 0, 0);
}

// ---------------- kernel 1: fp32 -> bf16 of x, W_qkv ----------------
__global__ __launch_bounds__(256) void prep_convert(const float* __restrict__ x,
                                                    const float* __restrict__ w,
                                                    u16* __restrict__ xbf,
                                                    u16* __restrict__ wbf) {
  const int nx = (4096 * DD) / 4;
  const int nw = (E3 * DD) / 4;
  int i = blockIdx.x * 256 + threadIdx.x;
  const float4* src;
  uint2* dst;
  int j;
  if (i < nx) { src = (const float4*)x; dst = (uint2*)xbf; j = i; }
  else if (i < nx + nw) { src = (const float4*)w; dst = (uint2*)wbf; j = i - nx; }
  else return;
  float4 v = src[j];
  unsigned lo = (unsigned)f2bf(v.x) | ((unsigned)f2bf(v.y) << 16);
  unsigned hi = (unsigned)f2bf(v.z) | ((unsigned)f2bf(v.w) << 16);
  dst[j] = make_uint2(lo, hi);
}

// ---------------- kernel 2: tqkv via MFMA, fp32 inputs converted in-register ----------------
__global__ __launch_bounds__(256) void tproj_mfma(const float* __restrict__ te,
                                                  const float* __restrict__ wt,
                                                  float* __restrict__ tq) {
  __shared__ u16 At[64][72];
  __shared__ u16 Bt[64][72];
  int bn = blockIdx.x;
  int tid = threadIdx.x;
  int w = tid >> 6, l = tid & 63;
  int l15 = l & 15, l16 = l >> 4;
  int r0 = tid >> 3, c0 = (tid & 7) * 8;
  f32x4 acc[4] = {};
  for (int kt = 0; kt < DD; kt += 64) {
    {
      const float* ta = &te[(size_t)r0 * DD + kt + c0];
      const float* tb = &te[(size_t)(r0 + 32) * DD + kt + c0];
      *(uint4*)&At[r0][c0]      = pack8(*(const float4*)ta, *(const float4*)(ta + 4));
      *(uint4*)&At[r0 + 32][c0] = pack8(*(const float4*)tb, *(const float4*)(tb + 4));
      const float* wa = &wt[(size_t)(bn * 64 + r0) * DD + kt + c0];
      const float* wb_ = &wt[(size_t)(bn * 64 + r0 + 32) * DD + kt + c0];
      *(uint4*)&Bt[r0][c0]      = pack8(*(const float4*)wa, *(const float4*)(wa + 4));
      *(uint4*)&Bt[r0 + 32][c0] = pack8(*(const float4*)wb_, *(const float4*)(wb_ + 4));
    }
    __syncthreads();
#pragma unroll
    for (int ks = 0; ks < 2; ++ks) {
      short8 bfr = *(const short8*)&Bt[w * 16 + l15][ks * 32 + l16 * 8];
#pragma unroll
      for (int mt = 0; mt < 4; ++mt) {
        short8 afr = *(const short8*)&At[mt * 16 + l15][ks * 32 + l16 * 8];
        acc[mt] = __builtin_amdgcn_mfma_f32_16x16x32_bf16(afr, bfr, acc[mt], 0, 0, 0);
      }
    }
    __syncthreads();
  }
  int e = bn * 64 + w * 16 + l15;
#pragma unroll
  for (int mt = 0; mt < 4; ++mt)
#pragma unroll
    for (int r = 0; r < 4; ++r)
      tq[(mt * 16 + l16 * 4 + r) * 192 + e] = acc[mt][r];
}

// ---------------- kernel 3: qkv GEMM (2-phase pipelined) + time add + scatter ----------------
__global__ __launch_bounds__(256) void gemm_qkv(const u16* __restrict__ xb,
                                                const u16* __restrict__ wb,
                                                const float* __restrict__ tq,
                                                u16* __restrict__ qp,
                                                u16* __restrict__ kp,
                                                u16* __restrict__ vt) {
  __shared__ u16 As[2][128][72];
  __shared__ u16 Bs[2][128][72];
  int bn = blockIdx.x;
  int bm = blockIdx.y;
  int tid = threadIdx.x;
  int w = tid >> 6, l = tid & 63;
  int wr = w >> 1, wc = w & 1;
  int l15 = l & 15, l16 = l >> 4;
  int r0 = tid >> 3, c0 = (tid & 7) * 8;

  f32x4 acc[4][4] = {};
  uint4 ra[4], rb[4];

#define LOADT(kt)                                                                    \
  {                                                                                  \
    _Pragma("unroll") for (int c = 0; c < 4; ++c) {                                  \
      ra[c] = *(const uint4*)&xb[(size_t)(bm * 128 + c * 32 + r0) * DD + (kt) + c0]; \
      rb[c] = *(const uint4*)&wb[(size_t)(bn * 128 + c * 32 + r0) * DD + (kt) + c0]; \
    }                                                                                \
  }
#define STORET(buf)                                                                  \
  {                                                                                  \
    _Pragma("unroll") for (int c = 0; c < 4; ++c) {                                  \
      *(uint4*)&As[buf][c * 32 + r0][c0] = ra[c];                                    \
      *(uint4*)&Bs[buf][c * 32 + r0][c0] = rb[c];                                    \
    }                                                                                \
  }

  LOADT(0);
  STORET(0);
  __syncthreads();
  int cur = 0;
#pragma unroll
  for (int i = 0; i < 8; ++i) {
    if (i < 7) LOADT((i + 1) * 64);
#pragma unroll
    for (int ks = 0; ks < 2; ++ks) {
      short8 af[4], bf[4];
#pragma unroll
      for (int mt = 0; mt < 4; ++mt)
        af[mt] = *(const short8*)&As[cur][wr * 64 + mt * 16 + l15][ks * 32 + l16 * 8];
#pragma unroll
      for (int nt = 0; nt < 4; ++nt)
        bf[nt] = *(const short8*)&Bs[cur][wc * 64 + nt * 16 + l15][ks * 32 + l16 * 8];
#pragma unroll
      for (int mt = 0; mt < 4; ++mt)
#pragma unroll
        for (int nt = 0; nt < 4; ++nt)
          acc[mt][nt] = __builtin_amdgcn_mfma_f32_16x16x32_bf16(af[mt], bf[nt], acc[mt][nt], 0, 0, 0);
    }
    if (i < 7) STORET(cur ^ 1);
    __syncthreads();
    cur ^= 1;
  }
#undef LOADT
#undef STORET

  int part = bn >> 2;
#pragma unroll
  for (int mt = 0; mt < 4; ++mt) {
    int m0 = bm * 128 + wr * 64 + mt * 16 + l16 * 4;
    int b = m0 >> 10;
    int li = (m0 >> 6) & 15;
    int nn0 = m0 & 1023;
    const float* tqrow = &tq[(b * LL + li) * 192 + part * 64];
#pragma unroll
    for (int nt = 0; nt < 4; ++nt) {
      int din = (bn & 3) * 128 + wc * 64 + nt * 16 + l15;
      int hh = din >> 6, hd = din & 63;
      float t = tqrow[hd];
      size_t bh = (size_t)(b * NH + hh);
      if (part == 2) {
        u16x4 pk;
#pragma unroll
        for (int r = 0; r < 4; ++r) pk[r] = f2bf(acc[mt][nt][r] + t);
        *(u16x4*)&vt[(bh * HDIM + hd) * NSEQ + nn0] = pk;
      } else {
        u16* dst = (part == 0) ? qp : kp;
#pragma unroll
        for (int r = 0; r < 4; ++r)
          dst[(bh * NSEQ + nn0 + r) * HDIM + hd] = f2bf(acc[mt][nt][r] + t);
      }
    }
  }
}

// ---------------- kernel 4: flash attention, S^T form, 1024 x 128-thread blocks ----------------
// Block = half of a (b,h,qf) tile: 2 waves, 32 KB LDS -> 4 blocks/CU, 8 waves/CU.
// Depth-2 stage pipeline with counted vmcnt(8); direct float4 O stores (no transpose).
__global__ __launch_bounds__(128, 2) void attn_kernel(const u16* __restrict__ qp,
                                                      const u16* __restrict__ kp,
                                                      const u16* __restrict__ vt,
                                                      const int* __restrict__ pos,
                                                      const float* __restrict__ emb,
                                                      float* __restrict__ out) {
  __shared__ __align__(16) u16 Kt[2][64][64];
  __shared__ __align__(16) u16 Vt[2][64][64];

  int blk = blockIdx.x;
  int qf = 15 - (blk >> 6);          // heavy first
  int bhid = (blk >> 1) & 31;
  int half = blk & 1;
  int b = bhid >> 3, h = bhid & 7;
  int tid = threadIdx.x;
  int rg = tid >> 6;                 // wave 0..1
  int l = tid & 63;
  int l15 = l & 15, l16 = l >> 4;
  int srow = l >> 3, c8 = l & 7;
  int schunk = c8 ^ srow;            // pre-swizzled global chunk
  int swzA = (l15 & 7) << 4;
  int rga = half * 2 + rg;           // absolute row-group 0..3

  size_t bh = (size_t)(b * NH + h);
  const u16* Kb = kp + bh * NSEQ * HDIM;
  const u16* Vb = vt + bh * HDIM * NSEQ;
  int rowl0 = rg * 16 + srow;        // wave rg covers rows rg*16+{0..15} and +32
  int rowl1 = rowl0 + 8;

#define STAGE(kf_, buf_)                                                       \
  {                                                                            \
    stage16(Kb + ((kf_) * 64 + rowl0) * HDIM + schunk * 8,                     \
            &Kt[buf_][rg * 16 + 0][0] + l * 8);                                \
    stage16(Kb + ((kf_) * 64 + rowl1) * HDIM + schunk * 8,                     \
            &Kt[buf_][rg * 16 + 8][0] + l * 8);                                \
    stage16(Kb + ((kf_) * 64 + rowl0 + 32) * HDIM + schunk * 8,                \
            &Kt[buf_][rg * 16 + 32][0] + l * 8);                               \
    stage16(Kb + ((kf_) * 64 + rowl1 + 32) * HDIM + schunk * 8,                \
            &Kt[buf_][rg * 16 + 40][0] + l * 8);                               \
    stage16(Vb + (size_t)rowl0 * NSEQ + (kf_) * 64 + schunk * 8,               \
            &Vt[buf_][rg * 16 + 0][0] + l * 8);                                \
    stage16(Vb + (size_t)rowl1 * NSEQ + (kf_) * 64 + schunk * 8,               \
            &Vt[buf_][rg * 16 + 8][0] + l * 8);                                \
    stage16(Vb + (size_t)(rowl0 + 32) * NSEQ + (kf_) * 64 + schunk * 8,        \
            &Vt[buf_][rg * 16 + 32][0] + l * 8);                               \
    stage16(Vb + (size_t)(rowl1 + 32) * NSEQ + (kf_) * 64 + schunk * 8,        \
            &Vt[buf_][rg * 16 + 40][0] + l * 8);                               \
  }

  // Q B-fragments (q = l15), registers for the whole kernel
  const u16* Qg = qp + (bh * NSEQ + qf * 64 + rga * 16) * HDIM;
  short8 aq[2];
  aq[0] = *(const short8*)&Qg[l15 * HDIM + l16 * 8];
  aq[1] = *(const short8*)&Qg[l15 * HDIM + 32 + l16 * 8];

  // depth-2 prologue
  STAGE(0, 0);
  if (qf > 0) STAGE(1, 1);

  // bias^T: bfragT holds bias[q=l15][kf = (lane>>4)*4 + reg]
  int pp = pos[(b * LL + qf) * LL + l15];
  pp = (pp < -8 ? -8 : (pp > 8 ? 8 : pp)) + 8;
  const float* ev = emb + pp * HDIM;
  f32x4 bfragT = {};
#pragma unroll
  for (int ks = 0; ks < 2; ++ks) {
    float4 e0 = *(const float4*)&ev[ks * 32 + l16 * 8];
    float4 e1 = *(const float4*)&ev[ks * 32 + l16 * 8 + 4];
    short8 ef;
    ef[0] = (short)f2bf(e0.x); ef[1] = (short)f2bf(e0.y);
    ef[2] = (short)f2bf(e0.z); ef[3] = (short)f2bf(e0.w);
    ef[4] = (short)f2bf(e1.x); ef[5] = (short)f2bf(e1.y);
    ef[6] = (short)f2bf(e1.z); ef[7] = (short)f2bf(e1.w);
    bfragT = __builtin_amdgcn_mfma_f32_16x16x32_bf16(ef, aq[ks], bfragT, 0, 0, 0);
  }

  f32x4 o[4] = {};
  float lsum = 0.f;

  if (qf > 0) { asm volatile("s_waitcnt vmcnt(8)" ::: "memory"); }
  else        { asm volatile("s_waitcnt vmcnt(0)" ::: "memory"); }
  __syncthreads();

  for (int kf = 0; kf <= qf; ++kf) {
    int cur = kf & 1;
    const char* ktb = (const char*)&Kt[cur][0][0];
    const char* vtb = (const char*)&Vt[cur][0][0];

    // S^T = mfma(K-rows, Q): s[nt][r] = S[q=l15][key = nt*16 + l16*4 + r]
    f32x4 s[4] = {};
    __builtin_amdgcn_s_setprio(1);
#pragma unroll
    for (int ks = 0; ks < 2; ++ks)
#pragma unroll
      for (int nt = 0; nt < 4; ++nt) {
        short8 kfrag = *(const short8*)(ktb + (nt * 16 + l15) * 128 + ((ks * 64 + l16 * 16) ^ swzA));
        s[nt] = __builtin_amdgcn_mfma_f32_16x16x32_bf16(kfrag, aq[ks], s[nt], 0, 0, 0);
      }
    __builtin_amdgcn_s_setprio(0);

    // one shuffle for the frame bias (per-lane q)
    float bb = __shfl(bfragT[kf & 3], ((kf >> 2) << 4) | l15) * INV_SCALE;

    float pv[4][4];
#pragma unroll
    for (int nt = 0; nt < 4; ++nt)
#pragma unroll
      for (int r = 0; r < 4; ++r) {
        float p = __expf(fmaf(s[nt][r], INV_SCALE, bb));
        pv[nt][r] = p;
        lsum += p;
      }

    // PV: pack own P values (no cross-lane), permuted V fragment reads
#pragma unroll
    for (int w32 = 0; w32 < 2; ++w32) {
      union { unsigned u[4]; short8 s8; } pf;
      pf.u[0] = cvtpk(pv[w32 * 2][0], pv[w32 * 2][1]);
      pf.u[1] = cvtpk(pv[w32 * 2][2], pv[w32 * 2][3]);
      pf.u[2] = cvtpk(pv[w32 * 2 + 1][0], pv[w32 * 2 + 1][1]);
      pf.u[3] = cvtpk(pv[w32 * 2 + 1][2], pv[w32 * 2 + 1][3]);
      int off0 = w32 * 64 + l16 * 8;
      int cp = off0 & ~15, sub = off0 & 15;
      __builtin_amdgcn_s_setprio(1);
#pragma unroll
      for (int dt = 0; dt < 4; ++dt) {
        int d = dt * 16 + l15;
        int sx = (d & 7) << 4;
        union { uint2 h2[2]; short8 s8; } vf;
        vf.h2[0] = *(const uint2*)(vtb + d * 128 + (cp ^ sx) + sub);
        vf.h2[1] = *(const uint2*)(vtb + d * 128 + ((cp + 32) ^ sx) + sub);
        o[dt] = __builtin_amdgcn_mfma_f32_16x16x32_bf16(vf.s8, pf.s8, o[dt], 0, 0, 0);
      }
      __builtin_amdgcn_s_setprio(0);
    }

    if (kf < qf) {
      __syncthreads();                       // all waves done reading buf cur
      if (kf + 2 <= qf) {
        STAGE(kf + 2, cur);                  // reuse cur for frame kf+2
        asm volatile("s_waitcnt vmcnt(8)" ::: "memory");   // STAGE(kf+1) landed
      } else {
        asm volatile("s_waitcnt vmcnt(0)" ::: "memory");
      }
      __syncthreads();
    }
  }
#undef STAGE

  // finish denominator: q=l15 partials live in lanes l15 + 16*{0..3}
  lsum += __shfl_xor(lsum, 16);
  lsum += __shfl_xor(lsum, 32);
  float inv = 1.0f / lsum;

  // direct O store: lane q=l15 owns d = dt*16 + l16*4 + {0..3} (consecutive)
  float* outp = out + ((size_t)(b * LL + qf) * 64 + rga * 16) * DD + h * 64;
#pragma unroll
  for (int dt = 0; dt < 4; ++dt) {
    float4 v;
    v.x = o[dt][0] * inv; v.y = o[dt][1] * inv;
    v.z = o[dt][2] * inv; v.w = o[dt][3] * inv;
    *(float4*)&outp[(size_t)l15 * DD + dt * 16 + l16 * 4] = v;
  }
}

// ---------------- launcher ----------------
extern "C" void kernel_launch(void* const* d_in, const int* in_sizes, int n_in,
                              void* d_out, int out_size, void* d_ws, size_t ws_size,
                              hipStream_t stream) {
  const float* x    = (const float*)d_in[0];
  const float* te   = (const float*)d_in[1];
  const int*   pos  = (const int*)d_in[2];
  // d_in[3] = mask: structurally frame-causal (tril)
  const float* wqkv = (const float*)d_in[4];
  const float* wt   = (const float*)d_in[5];
  const float* emb  = (const float*)d_in[6];
  float* out = (float*)d_out;
  char* ws = (char*)d_ws;

  const size_t OFF_XBF = 0;
  const size_t OFF_WBF  = OFF_XBF + (size_t)4096 * DD * 2;
  const size_t OFF_TQ   = OFF_WBF + (size_t)E3 * DD * 2;
  const size_t OFF_QKV  = OFF_TQ + (size_t)64 * 192 * 4;
  const size_t PLANE = (size_t)BB * NH * NSEQ * HDIM;

  u16*   xbf  = (u16*)(ws + OFF_XBF);
  u16*   wbf  = (u16*)(ws + OFF_WBF);
  float* tq   = (float*)(ws + OFF_TQ);
  u16*   qpl  = (u16*)(ws + OFF_QKV);
  u16*   kpl  = qpl + PLANE;
  u16*   vtl  = qpl + 2 * PLANE;

  prep_convert<<<2816, 256, 0, stream>>>(x, wqkv, xbf, wbf);
  tproj_mfma<<<3, 256, 0, stream>>>(te, wt, tq);
  gemm_qkv<<<dim3(12, 32), 256, 0, stream>>>(xbf, wbf, tq, qpl, kpl, vtl);
  attn_kernel<<<1024, 128, 0, stream>>>(qpl, kpl, vtl, pos, emb, out);
}

// Round 7
// 116.785 us; speedup vs baseline: 1.0464x; 1.0312x over previous
//
#include <hip/hip_runtime.h>

typedef unsigned short u16;
typedef __attribute__((ext_vector_type(8))) short short8;
typedef __attribute__((ext_vector_type(4))) float f32x4;
typedef __attribute__((ext_vector_type(4))) u16 u16x4;

#define BB 4
#define LL 16
#define DD 512
#define NH 8
#define HDIM 64
#define NSEQ 1024
#define E3 1536
#define INV_SCALE 0.04419417382415922f

__device__ __forceinline__ u16 f2bf(float f) {
  union { float f; unsigned u; } v; v.f = f;
  unsigned u = v.u;
  unsigned r = u + 0x7fffu + ((u >> 16) & 1u);
  return (u16)(r >> 16);
}

__device__ __forceinline__ unsigned cvtpk(float lo, float hi) {
  unsigned r;
  asm("v_cvt_pk_bf16_f32 %0, %1, %2" : "=v"(r) : "v"(lo), "v"(hi));
  return r;
}

__device__ __forceinline__ uint4 pack8(float4 a, float4 b) {
  uint4 r;
  r.x = (unsigned)f2bf(a.x) | ((unsigned)f2bf(a.y) << 16);
  r.y = (unsigned)f2bf(a.z) | ((unsigned)f2bf(a.w) << 16);
  r.z = (unsigned)f2bf(b.x) | ((unsigned)f2bf(b.y) << 16);
  r.w = (unsigned)f2bf(b.z) | ((unsigned)f2bf(b.w) << 16);
  return r;
}

__device__ __forceinline__ void stage16(const u16* g, u16* l) {
  __builtin_amdgcn_global_load_lds((const __attribute__((address_space(1))) unsigned int*)g,
                                   (__attribute__((address_space(3))) unsigned int*)l,
                                   16, 0, 0);
}

// ---------------- kernel 1: fp32->bf16 of x, W_qkv  (+3 tail blocks do tproj MFMA) ----------------
__global__ __launch_bounds__(256) void prep_tproj(const float* __restrict__ x,
                                                  const float* __restrict__ w,
                                                  const float* __restrict__ te,
                                                  const float* __restrict__ wt,
                                                  u16* __restrict__ xbf,
                                                  u16* __restrict__ wbf,
                                                  float* __restrict__ tq) {
  __shared__ u16 At[64][72];
  __shared__ u16 Bt[64][72];
  const int nx = (4096 * DD) / 4;   // 524288
  const int nw = (E3 * DD) / 4;     // 196608  (nx+nw = 720896 = 2816*256)
  int blk = blockIdx.x;
  int tid = threadIdx.x;

  if (blk < 2816) {
    int i = blk * 256 + tid;
    const float4* src;
    uint2* dst;
    int j;
    if (i < nx) { src = (const float4*)x; dst = (uint2*)xbf; j = i; }
    else { src = (const float4*)w; dst = (uint2*)wbf; j = i - nx; }
    float4 v = src[j];
    unsigned lo = (unsigned)f2bf(v.x) | ((unsigned)f2bf(v.y) << 16);
    unsigned hi = (unsigned)f2bf(v.z) | ((unsigned)f2bf(v.w) << 16);
    dst[j] = make_uint2(lo, hi);
    return;
  }

  // tproj: tq = te @ wt^T  ([64,512] x [192,512]^T), fp32 in, fp32 out
  int bn = blk - 2816;              // 0..2
  int w_ = tid >> 6, l = tid & 63;
  int l15 = l & 15, l16 = l >> 4;
  int r0 = tid >> 3, c0 = (tid & 7) * 8;
  f32x4 acc[4] = {};
  for (int kt = 0; kt < DD; kt += 64) {
    {
      const float* ta = &te[(size_t)r0 * DD + kt + c0];
      const float* tb = &te[(size_t)(r0 + 32) * DD + kt + c0];
      *(uint4*)&At[r0][c0]      = pack8(*(const float4*)ta, *(const float4*)(ta + 4));
      *(uint4*)&At[r0 + 32][c0] = pack8(*(const float4*)tb, *(const float4*)(tb + 4));
      const float* wa = &wt[(size_t)(bn * 64 + r0) * DD + kt + c0];
      const float* wb_ = &wt[(size_t)(bn * 64 + r0 + 32) * DD + kt + c0];
      *(uint4*)&Bt[r0][c0]      = pack8(*(const float4*)wa, *(const float4*)(wa + 4));
      *(uint4*)&Bt[r0 + 32][c0] = pack8(*(const float4*)wb_, *(const float4*)(wb_ + 4));
    }
    __syncthreads();
#pragma unroll
    for (int ks = 0; ks < 2; ++ks) {
      short8 bfr = *(const short8*)&Bt[w_ * 16 + l15][ks * 32 + l16 * 8];
#pragma unroll
      for (int mt = 0; mt < 4; ++mt) {
        short8 afr = *(const short8*)&At[mt * 16 + l15][ks * 32 + l16 * 8];
        acc[mt] = __builtin_amdgcn_mfma_f32_16x16x32_bf16(afr, bfr, acc[mt], 0, 0, 0);
      }
    }
    __syncthreads();
  }
  int e = bn * 64 + w_ * 16 + l15;
#pragma unroll
  for (int mt = 0; mt < 4; ++mt)
#pragma unroll
    for (int r = 0; r < 4; ++r)
      tq[(mt * 16 + l16 * 4 + r) * 192 + e] = acc[mt][r];
}

// ---------------- kernel 2: qkv GEMM (2-phase pipelined) + time add + LDS-coalesced stores ----------------
__global__ __launch_bounds__(256) void gemm_qkv(const u16* __restrict__ xb,
                                                const u16* __restrict__ wb,
                                                const float* __restrict__ tq,
                                                u16* __restrict__ qp,
                                                u16* __restrict__ kp,
                                                u16* __restrict__ vt) {
  __shared__ u16 As[2][128][72];
  __shared__ u16 Bs[2][128][72];
  int bn = blockIdx.x;   // 0..11
  int bm = blockIdx.y;   // 0..31
  int tid = threadIdx.x;
  int w = tid >> 6, l = tid & 63;
  int wr = w >> 1, wc = w & 1;
  int l15 = l & 15, l16 = l >> 4;
  int r0 = tid >> 3, c0 = (tid & 7) * 8;

  f32x4 acc[4][4] = {};
  uint4 ra[4], rb[4];

#define LOADT(kt)                                                                    \
  {                                                                                  \
    _Pragma("unroll") for (int c = 0; c < 4; ++c) {                                  \
      ra[c] = *(const uint4*)&xb[(size_t)(bm * 128 + c * 32 + r0) * DD + (kt) + c0]; \
      rb[c] = *(const uint4*)&wb[(size_t)(bn * 128 + c * 32 + r0) * DD + (kt) + c0]; \
    }                                                                                \
  }
#define STORET(buf)                                                                  \
  {                                                                                  \
    _Pragma("unroll") for (int c = 0; c < 4; ++c) {                                  \
      *(uint4*)&As[buf][c * 32 + r0][c0] = ra[c];                                    \
      *(uint4*)&Bs[buf][c * 32 + r0][c0] = rb[c];                                    \
    }                                                                                \
  }

  LOADT(0);
  STORET(0);
  __syncthreads();
  int cur = 0;
#pragma unroll
  for (int i = 0; i < 8; ++i) {
    if (i < 7) LOADT((i + 1) * 64);
#pragma unroll
    for (int ks = 0; ks < 2; ++ks) {
      short8 af[4], bf[4];
#pragma unroll
      for (int mt = 0; mt < 4; ++mt)
        af[mt] = *(const short8*)&As[cur][wr * 64 + mt * 16 + l15][ks * 32 + l16 * 8];
#pragma unroll
      for (int nt = 0; nt < 4; ++nt)
        bf[nt] = *(const short8*)&Bs[cur][wc * 64 + nt * 16 + l15][ks * 32 + l16 * 8];
#pragma unroll
      for (int mt = 0; mt < 4; ++mt)
#pragma unroll
        for (int nt = 0; nt < 4; ++nt)
          acc[mt][nt] = __builtin_amdgcn_mfma_f32_16x16x32_bf16(af[mt], bf[nt], acc[mt][nt], 0, 0, 0);
    }
    if (i < 7) STORET(cur ^ 1);
    __syncthreads();
    cur ^= 1;
  }
#undef LOADT
#undef STORET

  // ---- epilogue: time add, bf16 convert, stage through LDS, coalesced 16B stores ----
  int part = bn >> 2;                 // 0=q 1=k 2=v (block-uniform)
  int frame = bm * 2 + wr;            // global (b*16+li) for this wave's rows
  const float* tqrow = &tq[frame * 192 + part * 64];
  float tvals[4];
#pragma unroll
  for (int nt = 0; nt < 4; ++nt) tvals[nt] = tqrow[nt * 16 + l15];

  u16 (*E)[136] = (u16(*)[136])(&As[0][0][0]);   // 128x136 u16 = 34816B (fits in As)

  if (part == 2) {
    // transposed tile E[e][m]
#pragma unroll
    for (int mt = 0; mt < 4; ++mt)
#pragma unroll
      for (int nt = 0; nt < 4; ++nt)
#pragma unroll
        for (int r = 0; r < 4; ++r)
          E[wc * 64 + nt * 16 + l15][wr * 64 + mt * 16 + l16 * 4 + r] = f2bf(acc[mt][nt][r] + tvals[nt]);
  } else {
#pragma unroll
    for (int mt = 0; mt < 4; ++mt)
#pragma unroll
      for (int nt = 0; nt < 4; ++nt)
#pragma unroll
        for (int r = 0; r < 4; ++r)
          E[wr * 64 + mt * 16 + l16 * 4 + r][wc * 64 + nt * 16 + l15] = f2bf(acc[mt][nt][r] + tvals[nt]);
  }
  __syncthreads();

  int rlane = tid & 15;
  int b0 = bm >> 3;                   // batch (block-uniform)
  if (part == 2) {
    // v: E[e][m] -> vt[((b*8+hh)*64+hd)*1024 + (bm&7)*128 + m], 256B runs
#pragma unroll
    for (int pass = 0; pass < 8; ++pass) {
      int e = pass * 16 + (tid >> 4);
      int din = (bn & 3) * 128 + e;
      int hh = din >> 6, hd = din & 63;
      uint4 vv = *(const uint4*)&E[e][rlane * 8];
      size_t base = ((size_t)(b0 * NH + hh) * HDIM + hd) * NSEQ + (bm & 7) * 128 + rlane * 8;
      *(uint4*)&vt[base] = vv;
    }
  } else {
    u16* dst = (part == 0) ? qp : kp;
#pragma unroll
    for (int pass = 0; pass < 8; ++pass) {
      int m = pass * 16 + (tid >> 4);
      int e = rlane * 8;
      int din = (bn & 3) * 128 + e;
      int hh = din >> 6, hd = din & 63;
      int nn0 = (bm & 7) * 128 + m;
      uint4 vv = *(const uint4*)&E[m][e];
      *(uint4*)&dst[((size_t)(b0 * NH + hh) * NSEQ + nn0) * HDIM + hd] = vv;
    }
  }
}

// ---------------- kernel 3: flash attention, S^T form, 1024 x 128-thread blocks ----------------
__global__ __launch_bounds__(128, 2) void attn_kernel(const u16* __restrict__ qp,
                                                      const u16* __restrict__ kp,
                                                      const u16* __restrict__ vt,
                                                      const int* __restrict__ pos,
                                                      const float* __restrict__ emb,
                                                      float* __restrict__ out) {
  __shared__ __align__(16) u16 Kt[2][64][64];
  __shared__ __align__(16) u16 Vt[2][64][64];

  int blk = blockIdx.x;
  int qf = 15 - (blk >> 6);          // heavy first
  int bhid = (blk >> 1) & 31;
  int half = blk & 1;
  int b = bhid >> 3, h = bhid & 7;
  int tid = threadIdx.x;
  int rg = tid >> 6;                 // wave 0..1
  int l = tid & 63;
  int l15 = l & 15, l16 = l >> 4;
  int srow = l >> 3, c8 = l & 7;
  int schunk = c8 ^ srow;
  int swzA = (l15 & 7) << 4;
  int rga = half * 2 + rg;

  size_t bh = (size_t)(b * NH + h);
  const u16* Kb = kp + bh * NSEQ * HDIM;
  const u16* Vb = vt + bh * HDIM * NSEQ;
  int rowl0 = rg * 16 + srow;
  int rowl1 = rowl0 + 8;

#define STAGE(kf_, buf_)                                                       \
  {                                                                            \
    stage16(Kb + ((kf_) * 64 + rowl0) * HDIM + schunk * 8,                     \
            &Kt[buf_][rg * 16 + 0][0] + l * 8);                                \
    stage16(Kb + ((kf_) * 64 + rowl1) * HDIM + schunk * 8,                     \
            &Kt[buf_][rg * 16 + 8][0] + l * 8);                                \
    stage16(Kb + ((kf_) * 64 + rowl0 + 32) * HDIM + schunk * 8,                \
            &Kt[buf_][rg * 16 + 32][0] + l * 8);                               \
    stage16(Kb + ((kf_) * 64 + rowl1 + 32) * HDIM + schunk * 8,                \
            &Kt[buf_][rg * 16 + 40][0] + l * 8);                               \
    stage16(Vb + (size_t)rowl0 * NSEQ + (kf_) * 64 + schunk * 8,               \
            &Vt[buf_][rg * 16 + 0][0] + l * 8);                                \
    stage16(Vb + (size_t)rowl1 * NSEQ + (kf_) * 64 + schunk * 8,               \
            &Vt[buf_][rg * 16 + 8][0] + l * 8);                                \
    stage16(Vb + (size_t)(rowl0 + 32) * NSEQ + (kf_) * 64 + schunk * 8,        \
            &Vt[buf_][rg * 16 + 32][0] + l * 8);                               \
    stage16(Vb + (size_t)(rowl1 + 32) * NSEQ + (kf_) * 64 + schunk * 8,        \
            &Vt[buf_][rg * 16 + 40][0] + l * 8);                               \
  }

  const u16* Qg = qp + (bh * NSEQ + qf * 64 + rga * 16) * HDIM;
  short8 aq[2];
  aq[0] = *(const short8*)&Qg[l15 * HDIM + l16 * 8];
  aq[1] = *(const short8*)&Qg[l15 * HDIM + 32 + l16 * 8];

  STAGE(0, 0);
  if (qf > 0) STAGE(1, 1);

  int pp = pos[(b * LL + qf) * LL + l15];
  pp = (pp < -8 ? -8 : (pp > 8 ? 8 : pp)) + 8;
  const float* ev = emb + pp * HDIM;
  f32x4 bfragT = {};
#pragma unroll
  for (int ks = 0; ks < 2; ++ks) {
    float4 e0 = *(const float4*)&ev[ks * 32 + l16 * 8];
    float4 e1 = *(const float4*)&ev[ks * 32 + l16 * 8 + 4];
    short8 ef;
    ef[0] = (short)f2bf(e0.x); ef[1] = (short)f2bf(e0.y);
    ef[2] = (short)f2bf(e0.z); ef[3] = (short)f2bf(e0.w);
    ef[4] = (short)f2bf(e1.x); ef[5] = (short)f2bf(e1.y);
    ef[6] = (short)f2bf(e1.z); ef[7] = (short)f2bf(e1.w);
    bfragT = __builtin_amdgcn_mfma_f32_16x16x32_bf16(ef, aq[ks], bfragT, 0, 0, 0);
  }

  f32x4 o[4] = {};
  float lsum = 0.f;

  if (qf > 0) { asm volatile("s_waitcnt vmcnt(8)" ::: "memory"); }
  else        { asm volatile("s_waitcnt vmcnt(0)" ::: "memory"); }
  __syncthreads();

  for (int kf = 0; kf <= qf; ++kf) {
    int cur = kf & 1;
    const char* ktb = (const char*)&Kt[cur][0][0];
    const char* vtb = (const char*)&Vt[cur][0][0];

    f32x4 s[4] = {};
    __builtin_amdgcn_s_setprio(1);
#pragma unroll
    for (int ks = 0; ks < 2; ++ks)
#pragma unroll
      for (int nt = 0; nt < 4; ++nt) {
        short8 kfrag = *(const short8*)(ktb + (nt * 16 + l15) * 128 + ((ks * 64 + l16 * 16) ^ swzA));
        s[nt] = __builtin_amdgcn_mfma_f32_16x16x32_bf16(kfrag, aq[ks], s[nt], 0, 0, 0);
      }
    __builtin_amdgcn_s_setprio(0);

    float bb = __shfl(bfragT[kf & 3], ((kf >> 2) << 4) | l15) * INV_SCALE;

    float pv[4][4];
#pragma unroll
    for (int nt = 0; nt < 4; ++nt)
#pragma unroll
      for (int r = 0; r < 4; ++r) {
        float p = __expf(fmaf(s[nt][r], INV_SCALE, bb));
        pv[nt][r] = p;
        lsum += p;
      }

#pragma unroll
    for (int w32 = 0; w32 < 2; ++w32) {
      union { unsigned u[4]; short8 s8; } pf;
      pf.u[0] = cvtpk(pv[w32 * 2][0], pv[w32 * 2][1]);
      pf.u[1] = cvtpk(pv[w32 * 2][2], pv[w32 * 2][3]);
      pf.u[2] = cvtpk(pv[w32 * 2 + 1][0], pv[w32 * 2 + 1][1]);
      pf.u[3] = cvtpk(pv[w32 * 2 + 1][2], pv[w32 * 2 + 1][3]);
      int off0 = w32 * 64 + l16 * 8;
      int cp = off0 & ~15, sub = off0 & 15;
      __builtin_amdgcn_s_setprio(1);
#pragma unroll
      for (int dt = 0; dt < 4; ++dt) {
        int d = dt * 16 + l15;
        int sx = (d & 7) << 4;
        union { uint2 h2[2]; short8 s8; } vf;
        vf.h2[0] = *(const uint2*)(vtb + d * 128 + (cp ^ sx) + sub);
        vf.h2[1] = *(const uint2*)(vtb + d * 128 + ((cp + 32) ^ sx) + sub);
        o[dt] = __builtin_amdgcn_mfma_f32_16x16x32_bf16(vf.s8, pf.s8, o[dt], 0, 0, 0);
      }
      __builtin_amdgcn_s_setprio(0);
    }

    if (kf < qf) {
      __syncthreads();
      if (kf + 2 <= qf) {
        STAGE(kf + 2, cur);
        asm volatile("s_waitcnt vmcnt(8)" ::: "memory");
      } else {
        asm volatile("s_waitcnt vmcnt(0)" ::: "memory");
      }
      __syncthreads();
    }
  }
#undef STAGE

  lsum += __shfl_xor(lsum, 16);
  lsum += __shfl_xor(lsum, 32);
  float inv = 1.0f / lsum;

  float* outp = out + ((size_t)(b * LL + qf) * 64 + rga * 16) * DD + h * 64;
#pragma unroll
  for (int dt = 0; dt < 4; ++dt) {
    float4 v;
    v.x = o[dt][0] * inv; v.y = o[dt][1] * inv;
    v.z = o[dt][2] * inv; v.w = o[dt][3] * inv;
    *(float4*)&outp[(size_t)l15 * DD + dt * 16 + l16 * 4] = v;
  }
}

// ---------------- launcher ----------------
extern "C" void kernel_launch(void* const* d_in, const int* in_sizes, int n_in,
                              void* d_out, int out_size, void* d_ws, size_t ws_size,
                              hipStream_t stream) {
  const float* x    = (const float*)d_in[0];
  const float* te   = (const float*)d_in[1];
  const int*   pos  = (const int*)d_in[2];
  // d_in[3] = mask: structurally frame-causal (tril)
  const float* wqkv = (const float*)d_in[4];
  const float* wt   = (const float*)d_in[5];
  const float* emb  = (const float*)d_in[6];
  float* out = (float*)d_out;
  char* ws = (char*)d_ws;

  const size_t OFF_XBF = 0;
  const size_t OFF_WBF  = OFF_XBF + (size_t)4096 * DD * 2;
  const size_t OFF_TQ   = OFF_WBF + (size_t)E3 * DD * 2;
  const size_t OFF_QKV  = OFF_TQ + (size_t)64 * 192 * 4;
  const size_t PLANE = (size_t)BB * NH * NSEQ * HDIM;

  u16*   xbf  = (u16*)(ws + OFF_XBF);
  u16*   wbf  = (u16*)(ws + OFF_WBF);
  float* tq   = (float*)(ws + OFF_TQ);
  u16*   qpl  = (u16*)(ws + OFF_QKV);
  u16*   kpl  = qpl + PLANE;
  u16*   vtl  = qpl + 2 * PLANE;

  prep_tproj<<<2819, 256, 0, stream>>>(x, wqkv, te, wt, xbf, wbf, tq);
  gemm_qkv<<<dim3(12, 32), 256, 0, stream>>>(xbf, wbf, tq, qpl, kpl, vtl);
  attn_kernel<<<1024, 128, 0, stream>>>(qpl, kpl, vtl, pos, emb, out);
}